// Round 14
// baseline (340.362 us; speedup 1.0000x reference)
//
#include <hip/hip_runtime.h>
#include <hip/hip_bf16.h>

#define LEAKC 0.1f

__device__ __forceinline__ float lrelu(float v){ return v > 0.f ? v : LEAKC*v; }
__device__ __forceinline__ ushort f2b(float f){
  __hip_bfloat16 h = __float2bfloat16(f);
  return *reinterpret_cast<ushort*>(&h);
}
__device__ __forceinline__ float b2f(ushort u){
  __hip_bfloat16 h = *reinterpret_cast<__hip_bfloat16*>(&u);
  return __bfloat162float(h);
}

typedef __attribute__((ext_vector_type(8))) short bf16x8;
typedef __attribute__((ext_vector_type(4))) float f32x4;

// ---------------- setup: block0 = styles + map1 + map2; block1 = cls counting sort ----------------
__global__ __launch_bounds__(256) void setup_kernel(
    const float* __restrict__ g, const float* __restrict__ sp1, const float* __restrict__ sp2,
    const float* __restrict__ c1w1, const float* __restrict__ c1b1,
    const float* __restrict__ c2w,  const float* __restrict__ c2b,
    const float* __restrict__ label,
    float* __restrict__ map1, float* __restrict__ map2,
    int* __restrict__ clsb, int* __restrict__ cnt, int* __restrict__ off, int* __restrict__ order){
  int t = threadIdx.x;
  if (blockIdx.x == 0){
    __shared__ float s1s[64], s2s[128];
    if (t < 64){
      int b = t >> 5, j = t & 31;
      float a = 0.f;
      for (int k=0;k<256;k++) a += g[b*256+k]*sp1[j*256+k];
      s1s[t] = a;
    } else if (t < 192){
      int u = t - 64;
      int b = u >> 6, j = u & 63;
      float a = 0.f;
      for (int k=0;k<256;k++) a += g[b*256+k]*sp2[j*256+k];
      s2s[u] = a;
    }
    __syncthreads();
    if (t < 128){           // map1
      int b = t >> 6, o = t & 63;
      float S0=0.f,S1=0.f,S2=0.f;
      for (int c=0;c<32;c++){
        float s = s1s[b*32+c];
        const float* wq = c1w1 + ((size_t)o*96 + 64 + c)*9;
        S0 += s*(wq[0]+wq[3]+wq[6]);
        S1 += s*(wq[1]+wq[4]+wq[7]);
        S2 += s*(wq[2]+wq[5]+wq[8]);
      }
      float bb = c1b1[o];
      map1[t*3+0]=S1+S2+bb; map1[t*3+1]=S0+S1+S2+bb; map1[t*3+2]=S0+S1+bb;
    }
    {                        // map2
      int b = t >> 7, o = t & 127;
      float S0=0.f,S1=0.f,S2=0.f;
      for (int c=0;c<64;c++){
        float s = s2s[b*64+c];
        const float* wq = c2w + ((size_t)o*192 + 128 + c)*9;
        S0 += s*(wq[0]+wq[3]+wq[6]);
        S1 += s*(wq[1]+wq[4]+wq[7]);
        S2 += s*(wq[2]+wq[5]+wq[8]);
      }
      float bb = c2b[o];
      map2[t*3+0]=S1+S2+bb; map2[t*3+1]=S0+S1+S2+bb; map2[t*3+2]=S0+S1+bb;
    }
  } else {
    __shared__ int h[80], hoff[80];
    if (t < 80) h[t] = 0;
    __syncthreads();
    int b = t >> 7, tt = t & 127;
    const float* p = label + (tt*2 + b)*80;
    float best = p[0]; int bi = 0;
    for (int c=1;c<80;c++){ float v = p[c]; if (v > best){ best = v; bi = c; } }
    clsb[t] = bi;
    atomicAdd(&h[bi], 1);
    __syncthreads();
    if (t == 0){
      int s = 0;
      for (int e=0;e<80;e++){ hoff[e] = s; s += h[e]; }
    }
    __syncthreads();
    if (t < 80){ cnt[t] = h[t]; off[t] = hoff[t]; }
    __syncthreads();
    int rank = atomicAdd(&hoff[bi], 1);
    order[rank] = t;
  }
}

// ---------------- one repack kernel for all 5 weight tensors ----------------
__device__ __forceinline__ void pack1(int idx, const float* __restrict__ w,
                                      ushort* __restrict__ wb, int CM, int CTOT){
  int c = idx % CM; int r = idx / CM; int t = r % 9; int n = r / 9;
  wb[idx] = f2b(w[((size_t)n*CTOT + c)*9 + t]);
}
__global__ void repack_all(const float* __restrict__ c1w1, const float* __restrict__ c1w2,
                           const float* __restrict__ c2w,  const float* __restrict__ c3w1,
                           const float* __restrict__ c3w2,
                           ushort* __restrict__ Wb2, ushort* __restrict__ Wb4,
                           ushort* __restrict__ Wb5, ushort* __restrict__ Wb6,
                           ushort* __restrict__ Wb7){
  int i = blockIdx.x*256 + threadIdx.x;
  if      (i < 36864)  pack1(i,        c1w1, Wb2, 64, 96);
  else if (i < 110592) pack1(i-36864,  c1w2, Wb4, 64, 64);
  else if (i < 258048) pack1(i-110592, c2w,  Wb5, 128, 192);
  else if (i < 405504) pack1(i-258048, c3w1, Wb6, 128, 240);
  else if (i < 700416) pack1(i-405504, c3w2, Wb7, 128, 128);
}

// ---------------- input conv 7x7 -> bf16, LDS-staged x window ----------------
__global__ __launch_bounds__(256) void conv_in_kernel(const float* __restrict__ x,
                               const float* __restrict__ wgt,
                               const float* __restrict__ bias,
                               ushort* __restrict__ out){
  __shared__ float xs[7][264];
  int tid = threadIdx.x;
  int w0 = (blockIdx.x & 1)*256;
  int y  = blockIdx.x >> 1;            // 0..57
  int b  = blockIdx.z;
  int o0 = blockIdx.y * 8;
  for (int i = tid; i < 7*262; i += 256){
    int r = i/262, c = i - r*262;
    int wg = w0 + c - 3;
    xs[r][c] = (wg >= 0 && wg < 512) ? x[((size_t)b*64 + y + r)*512 + wg] : 0.f;
  }
  __syncthreads();
  int w = w0 + tid;
  float acc[8];
  #pragma unroll
  for (int i=0;i<8;i++) acc[i] = bias[o0+i];
  #pragma unroll
  for (int kh=0;kh<7;kh++){
    #pragma unroll
    for (int kw=0;kw<7;kw++){
      float v = xs[kh][tid + kw];
      #pragma unroll
      for (int i=0;i<8;i++) acc[i] += v * wgt[(o0+i)*49 + kh*7 + kw];
    }
  }
  #pragma unroll
  for (int i=0;i<8;i++)
    out[((b*64 + o0+i)*58 + y)*512 + w] = f2b(lrelu(acc[i]));
}

// ---------------- MFMA conv (no pool): 3x3, pad(0,1), BM=64, BN=64 ----------------
template<int CM,int WID,int HIN,int COUT,int MODE,int OUTBF>
__global__ __launch_bounds__(256) void conv_mfma(
    const ushort* __restrict__ in,
    const ushort* __restrict__ Wb,
    const float*  __restrict__ mb,
    float* __restrict__ outf,
    ushort* __restrict__ outh){
  constexpr int HOUT = HIN - 2;
  constexpr int KTOT = CM*9;
  constexpr int SLABS = CM/32;
  constexpr int NST = 3*SLABS;
  __shared__ ushort A[2][66][40];
  int tid = threadIdx.x, lane = tid & 63, wave = tid >> 6;
  int mt = blockIdx.x;
  int y  = mt / (WID/64), w0 = (mt % (WID/64))*64;
  int n0 = blockIdx.y*64;
  int b  = blockIdx.z;

  f32x4 acc[4];
  #pragma unroll
  for (int nf=0;nf<4;nf++) acc[nf] = (f32x4){0.f,0.f,0.f,0.f};

  auto stage = [&](int s, int bufi){
    int kh = s / SLABS;
    int c0 = (s % SLABS)*32;
    const ushort* base = in + ((size_t)(b*CM + c0)*HIN + (y+kh))*WID;
    int c2 = (tid & 15)*2, m0v = (tid >> 4)*2*2;
    const ushort* p0 = base + (size_t)c2*HIN*WID + w0 + m0v;
    const ushort* p1 = p0 + (size_t)HIN*WID;
    ushort4 va = *(const ushort4*)p0;
    ushort4 vb = *(const ushort4*)p1;
    uint* dst = (uint*)&A[bufi][1+m0v][c2];
    dst[0]  = (uint)va.x | ((uint)vb.x << 16);
    dst[20] = (uint)va.y | ((uint)vb.y << 16);
    dst[40] = (uint)va.z | ((uint)vb.z << 16);
    dst[60] = (uint)va.w | ((uint)vb.w << 16);
    if (tid < 64){
      int c = tid & 31, side = tid >> 5;
      int w = side ? (w0 + 64) : (w0 - 1);
      ushort v = 0;
      if (w >= 0 && w < WID) v = base[(size_t)c*HIN*WID + w];
      A[bufi][side ? 65 : 0][c] = v;
    }
  };

  stage(0, 0);
  __syncthreads();
  for (int s = 0; s < NST; ++s){
    int cur = s & 1;
    if (s + 1 < NST) stage(s+1, cur ^ 1);
    int kh = s / SLABS;
    int c0 = (s % SLABS)*32;
    #pragma unroll
    for (int kw = 0; kw < 3; ++kw){
      bf16x8 a = *(bf16x8*)&A[cur][wave*16 + (lane & 15) + kw][(lane >> 4)*8];
      #pragma unroll
      for (int nf = 0; nf < 4; ++nf){
        const ushort* wp = Wb + (size_t)(n0 + nf*16 + (lane & 15))*KTOT
                              + (kh*3 + kw)*CM + c0 + (lane >> 4)*8;
        bf16x8 bb = *(const bf16x8*)wp;
        acc[nf] = __builtin_amdgcn_mfma_f32_16x16x32_bf16(a, bb, acc[nf], 0, 0, 0);
      }
    }
    __syncthreads();
  }

  int mrow = wave*16 + ((lane >> 4) << 2);
  int w = w0 + mrow;
  #pragma unroll
  for (int nf = 0; nf < 4; ++nf){
    int n = n0 + nf*16 + (lane & 15);
    float r0 = acc[nf][0], r1 = acc[nf][1], r2 = acc[nf][2], r3 = acc[nf][3];
    if (MODE == 0){
      float bb = mb[n];
      r0 += bb; r1 += bb; r2 += bb; r3 += bb;
    } else if (MODE == 1){
      const float* m3 = mb + (size_t)(b*COUT + n)*3;
      float mL = m3[0], mM = m3[1], mR = m3[2];
      r0 += (w == 0) ? mL : ((w   == WID-1) ? mR : mM);
      r1 += (w+1 == WID-1) ? mR : mM;
      r2 += (w+2 == WID-1) ? mR : mM;
      r3 += (w+3 == WID-1) ? mR : mM;
    } else {
      const float* m6 = mb + ((size_t)(b*COUT + n))*WID + w;
      r0 += m6[0]; r1 += m6[1]; r2 += m6[2]; r3 += m6[3];
    }
    r0 = lrelu(r0); r1 = lrelu(r1); r2 = lrelu(r2); r3 = lrelu(r3);
    size_t off = ((size_t)(b*COUT + n)*HOUT + y)*WID + w;
    if (OUTBF){
      ushort4 o = make_ushort4(f2b(r0), f2b(r1), f2b(r2), f2b(r3));
      *(ushort4*)(outh + off) = o;
    } else {
      *(float4*)(outf + off) = make_float4(r0, r1, r2, r3);
    }
  }
}

// ---------------- MFMA conv + 2x2 mean-pool fused: writes pooled bf16 ----------------
// Block computes rows y=2*yp, 2*yp+1 (two K-pipeline passes) and pools in-register.
template<int CM,int WID,int HIN,int COUT,int MODE>
__global__ __launch_bounds__(256) void conv_mfma_pool(
    const ushort* __restrict__ in,
    const ushort* __restrict__ Wb,
    const float*  __restrict__ mb,
    ushort* __restrict__ outp){   // (2,COUT,HOUT/2,WID/2)
  constexpr int HOUT = HIN - 2;
  constexpr int HP = HOUT/2;
  constexpr int WP = WID/2;
  constexpr int KTOT = CM*9;
  constexpr int SLABS = CM/32;
  constexpr int NST = 3*SLABS;
  __shared__ ushort A[2][66][40];
  int tid = threadIdx.x, lane = tid & 63, wave = tid >> 6;
  int mt = blockIdx.x;
  int yp = mt / (WID/64), w0 = (mt % (WID/64))*64;
  int n0 = blockIdx.y*64;
  int b  = blockIdx.z;

  float pacc[4][2];
  #pragma unroll
  for (int nf=0;nf<4;nf++){ pacc[nf][0]=0.f; pacc[nf][1]=0.f; }

  int mrow = wave*16 + ((lane >> 4) << 2);
  int w = w0 + mrow;

  for (int ky = 0; ky < 2; ++ky){
    int y = 2*yp + ky;
    f32x4 acc[4];
    #pragma unroll
    for (int nf=0;nf<4;nf++) acc[nf] = (f32x4){0.f,0.f,0.f,0.f};

    auto stage = [&](int s, int bufi){
      int kh = s / SLABS;
      int c0 = (s % SLABS)*32;
      const ushort* base = in + ((size_t)(b*CM + c0)*HIN + (y+kh))*WID;
      int c2 = (tid & 15)*2, m0v = (tid >> 4)*2*2;
      const ushort* p0 = base + (size_t)c2*HIN*WID + w0 + m0v;
      const ushort* p1 = p0 + (size_t)HIN*WID;
      ushort4 va = *(const ushort4*)p0;
      ushort4 vb = *(const ushort4*)p1;
      uint* dst = (uint*)&A[bufi][1+m0v][c2];
      dst[0]  = (uint)va.x | ((uint)vb.x << 16);
      dst[20] = (uint)va.y | ((uint)vb.y << 16);
      dst[40] = (uint)va.z | ((uint)vb.z << 16);
      dst[60] = (uint)va.w | ((uint)vb.w << 16);
      if (tid < 64){
        int c = tid & 31, side = tid >> 5;
        int ww = side ? (w0 + 64) : (w0 - 1);
        ushort v = 0;
        if (ww >= 0 && ww < WID) v = base[(size_t)c*HIN*WID + ww];
        A[bufi][side ? 65 : 0][c] = v;
      }
    };

    stage(0, 0);
    __syncthreads();
    for (int s = 0; s < NST; ++s){
      int cur = s & 1;
      if (s + 1 < NST) stage(s+1, cur ^ 1);
      int kh = s / SLABS;
      int c0 = (s % SLABS)*32;
      #pragma unroll
      for (int kw = 0; kw < 3; ++kw){
        bf16x8 a = *(bf16x8*)&A[cur][wave*16 + (lane & 15) + kw][(lane >> 4)*8];
        #pragma unroll
        for (int nf = 0; nf < 4; ++nf){
          const ushort* wp = Wb + (size_t)(n0 + nf*16 + (lane & 15))*KTOT
                                + (kh*3 + kw)*CM + c0 + (lane >> 4)*8;
          bf16x8 bb = *(const bf16x8*)wp;
          acc[nf] = __builtin_amdgcn_mfma_f32_16x16x32_bf16(a, bb, acc[nf], 0, 0, 0);
        }
      }
      __syncthreads();
    }

    #pragma unroll
    for (int nf = 0; nf < 4; ++nf){
      int n = n0 + nf*16 + (lane & 15);
      float r0 = acc[nf][0], r1 = acc[nf][1], r2 = acc[nf][2], r3 = acc[nf][3];
      if (MODE == 0){
        float bb = mb[n];
        r0 += bb; r1 += bb; r2 += bb; r3 += bb;
      } else if (MODE == 1){
        const float* m3 = mb + (size_t)(b*COUT + n)*3;
        float mL = m3[0], mM = m3[1], mR = m3[2];
        r0 += (w == 0) ? mL : ((w   == WID-1) ? mR : mM);
        r1 += (w+1 == WID-1) ? mR : mM;
        r2 += (w+2 == WID-1) ? mR : mM;
        r3 += (w+3 == WID-1) ? mR : mM;
      } else {
        const float* m6 = mb + ((size_t)(b*COUT + n))*WID + w;
        r0 += m6[0]; r1 += m6[1]; r2 += m6[2]; r3 += m6[3];
      }
      r0 = lrelu(r0); r1 = lrelu(r1); r2 = lrelu(r2); r3 = lrelu(r3);
      pacc[nf][0] += r0 + r1;
      pacc[nf][1] += r2 + r3;
    }
  }

  int wp2 = (w0 + mrow) >> 1;
  #pragma unroll
  for (int nf = 0; nf < 4; ++nf){
    int n = n0 + nf*16 + (lane & 15);
    ushort2 o = make_ushort2(f2b(pacc[nf][0]*0.25f), f2b(pacc[nf][1]*0.25f));
    *(ushort2*)(outp + ((size_t)(b*COUT + n)*HP + yp)*WP + wp2) = o;
  }
}

// ---------------- A6 column map (includes bias) ----------------
__global__ void map6_kernel(const float* __restrict__ spaced,
                            const float* __restrict__ label,
                            const float* __restrict__ wgt,
                            const float* __restrict__ bias,
                            float* __restrict__ mapv){
  int n = blockIdx.x*256 + threadIdx.x;
  int w = n & 127, o = (n >> 7) & 127, b = n >> 14;
  float a = bias[o];
  #pragma unroll
  for (int t=0;t<3;t++){
    int j = w + t - 1;
    if (j < 0 || j >= 128) continue;
    const float* sp = spaced + (j*2 + b)*32;
    const float* lb = label + (j*2 + b)*80;
    for (int c=0;c<32;c++){
      const float* wq = wgt + ((size_t)o*240 + 128 + c)*9 + t;
      a += sp[c]*(wq[0]+wq[3]+wq[6]);
    }
    for (int c=0;c<80;c++){
      const float* wq = wgt + ((size_t)o*240 + 160 + c)*9 + t;
      a += lb[c]*(wq[0]+wq[3]+wq[6]);
    }
  }
  mapv[n] = a;
}

// ---------------- pM ----------------
__global__ __launch_bounds__(256) void fm_kernel(const float* __restrict__ A7,
                          const float* __restrict__ fw,
                          const float* __restrict__ fb,
                          float* __restrict__ out){
  __shared__ float red[4];
  int n = blockIdx.x;
  int b = n >> 6, w = n & 63;
  int c = threadIdx.x;
  float a = 0.f;
  #pragma unroll
  for (int r=0;r<3;r++){
    const float* ip = A7 + ((b*256+c)*3+r)*64;
    const float* wp = fw + (c*3+r)*3;
    #pragma unroll
    for (int kw=0;kw<3;kw++){
      int wi = w + kw - 1;
      if (wi>=0 && wi<64) a += ip[wi]*wp[kw];
    }
  }
  #pragma unroll
  for (int off=32; off>0; off>>=1) a += __shfl_down(a, off, 64);
  if ((threadIdx.x & 63) == 0) red[threadIdx.x>>6] = a;
  __syncthreads();
  if (threadIdx.x == 0) out[n] = red[0]+red[1]+red[2]+red[3] + fb[0];
}

// ---------------- im2col -> bf16: pwgh[n][j][d] (d = c*9 + r*3 + kw) ----------------
__global__ void im2col_kernel(const float* __restrict__ A7, ushort* __restrict__ pwgh){
  int i = blockIdx.x*256 + threadIdx.x;
  if (i >= 256*3*2304) return;
  int d = i % 2304; int rj = i / 2304; int j = rj % 3; int n = rj / 3;
  int b = n >> 7, t = n & 127; int idx = t >> 1;
  int c = d / 9, rem = d - c*9, r = rem / 3, kw = rem - r*3;
  int col = idx - 2 + kw + j;
  pwgh[i] = (col >= 0 && col < 64) ? f2b(A7[((size_t)(b*256 + c)*3 + r)*64 + col]) : (ushort)0;
}

// ---------------- cd conv v6: grouped-GEMM MFMA, uniform work, weights once ----------------
__global__ __launch_bounds__(256) void cd_conv_kernel(
    const ushort* __restrict__ pwgh,  // (256,3,2304) bf16
    const int*   __restrict__ cnt,    // (80)
    const int*   __restrict__ offv,   // (80)
    const int*   __restrict__ order,  // (256)
    const float* __restrict__ Wc,     // (80,128,2304) f32
    float* __restrict__ comat)        // (256,128,3) raw conv outputs
{
  __shared__ int rowOff[48];
  __shared__ f32x4 red[4][3][64];
  int e = blockIdx.x, og = blockIdx.y;
  int m = cnt[e];
  if (m == 0) return;
  int base = offv[e];
  int tid = threadIdx.x, lane = tid & 63, wave = tid >> 6;

  const float* wb_base = Wc + ((size_t)(e*128) + og*16 + (lane & 15))*2304;
  int kbase = wave*576 + ((lane >> 4)*8);

  for (int s0 = 0; s0 < m; s0 += 16){
    int rowsChunk = 3*(m - s0); if (rowsChunk > 48) rowsChunk = 48;
    if (tid < 48){
      int lr = s0 + tid/3;
      rowOff[tid] = (lr < m) ? (order[base+lr]*3 + (tid - (tid/3)*3))*2304 : -1;
    }
    __syncthreads();

    int offA[3];
    #pragma unroll
    for (int mt=0; mt<3; mt++) offA[mt] = rowOff[mt*16 + (lane & 15)];

    f32x4 acc[3];
    #pragma unroll
    for (int mt=0; mt<3; mt++) acc[mt] = (f32x4){0.f,0.f,0.f,0.f};

    for (int kk = 0; kk < 18; ++kk){
      int k0 = kbase + kk*32;
      const float* wb = wb_base + k0;
      float4 wv0 = *(const float4*)wb;
      float4 wv1 = *(const float4*)(wb + 4);
      bf16x8 bfr = { (short)f2b(wv0.x), (short)f2b(wv0.y), (short)f2b(wv0.z), (short)f2b(wv0.w),
                     (short)f2b(wv1.x), (short)f2b(wv1.y), (short)f2b(wv1.z), (short)f2b(wv1.w) };
      #pragma unroll
      for (int mt=0; mt<3; mt++){
        if (mt*16 < rowsChunk){
          bf16x8 af = {0,0,0,0,0,0,0,0};
          if (offA[mt] >= 0) af = *(const bf16x8*)&pwgh[offA[mt] + k0];
          acc[mt] = __builtin_amdgcn_mfma_f32_16x16x32_bf16(af, bfr, acc[mt], 0, 0, 0);
        }
      }
    }

    #pragma unroll
    for (int mt=0; mt<3; mt++) red[wave][mt][lane] = acc[mt];
    __syncthreads();

    if (wave < 3){
      int mt = wave;
      if (mt*16 < rowsChunk){
        f32x4 s4 = red[0][mt][lane];
        #pragma unroll
        for (int w2=1; w2<4; w2++){
          f32x4 t4 = red[w2][mt][lane];
          s4[0]+=t4[0]; s4[1]+=t4[1]; s4[2]+=t4[2]; s4[3]+=t4[3];
        }
        int col = og*16 + (lane & 15);
        #pragma unroll
        for (int r=0; r<4; r++){
          int row = mt*16 + ((lane >> 4) << 2) + r;
          if (row < rowsChunk){
            int lrank = s0 + row/3, j = row - (row/3)*3;
            int n = order[base + lrank];
            comat[((size_t)n*128 + col)*3 + j] = s4[r];
          }
        }
      }
    }
    __syncthreads();
  }
}

// ---------------- cd tail: comat -> pooled feat -> fc1 -> fc2 ----------------
__global__ __launch_bounds__(128) void cd_tail_kernel(
    const float* __restrict__ comat,
    const int*   __restrict__ clsb,
    const float* __restrict__ bcv,
    const float* __restrict__ cstyle,
    const float* __restrict__ W1,
    const float* __restrict__ b1,
    const float* __restrict__ W2,
    const float* __restrict__ b2,
    float* __restrict__ pChar)
{
  __shared__ float feat[160];
  __shared__ float red2[2];
  int n = blockIdx.x, tid = threadIdx.x;
  int b = n >> 7;
  int e = clsb[n];
  int o = tid;
  const float* cm = comat + ((size_t)n*128 + o)*3;
  float bb = bcv[e*128 + o];
  feat[o] = (lrelu(cm[0]+bb) + lrelu(cm[1]+bb) + lrelu(cm[2]+bb)) * (1.f/3.f);
  if (tid < 32) feat[128+tid] = cstyle[(b*80 + e)*32 + tid];
  __syncthreads();

  float s = b1[e*128 + o];
  for (int d=0;d<160;d++) s += feat[d]*W1[(e*160 + d)*128 + o];
  float h = s > 0.f ? s : 0.f;
  float contrib = h * W2[e*128 + o];
  #pragma unroll
  for (int off=32; off>0; off>>=1) contrib += __shfl_down(contrib, off, 64);
  if ((tid & 63) == 0) red2[tid>>6] = contrib;
  __syncthreads();
  if (tid == 0) pChar[n] = red2[0] + red2[1] + b2[e];
}

extern "C" void kernel_launch(void* const* d_in, const int* in_sizes, int n_in,
                              void* d_out, int out_size, void* d_ws, size_t ws_size,
                              hipStream_t stream){
  (void)in_sizes; (void)n_in; (void)out_size; (void)ws_size;
  const float* x      = (const float*)d_in[0];
  const float* label  = (const float*)d_in[1];
  const float* g_style= (const float*)d_in[2];
  const float* spaced = (const float*)d_in[3];
  const float* cstyle = (const float*)d_in[4];
  const float* sp1    = (const float*)d_in[5];
  const float* sp2    = (const float*)d_in[6];
  const float* in_w   = (const float*)d_in[7];
  const float* in_b   = (const float*)d_in[8];
  const float* c1w1   = (const float*)d_in[9];
  const float* c1b1   = (const float*)d_in[10];
  const float* c1w2   = (const float*)d_in[11];
  const float* c1b2   = (const float*)d_in[12];
  const float* c2w    = (const float*)d_in[13];
  const float* c2b    = (const float*)d_in[14];
  const float* c3w1   = (const float*)d_in[15];
  const float* c3b1   = (const float*)d_in[16];
  const float* c3w2   = (const float*)d_in[17];
  const float* c3b2   = (const float*)d_in[18];
  const float* fm_w   = (const float*)d_in[19];
  const float* fm_b   = (const float*)d_in[20];
  const float* cdw    = (const float*)d_in[21];
  const float* cdb    = (const float*)d_in[22];
  const float* fc1w   = (const float*)d_in[23];
  const float* fc1b   = (const float*)d_in[24];
  const float* fc2w   = (const float*)d_in[25];
  const float* fc2b   = (const float*)d_in[26];
  float* out = (float*)d_out;
  char* ws = (char*)d_ws;

  ushort* h1b  = (ushort*)(ws + 0);                // 7,602,176
  ushort* pwgh = (ushort*)(ws + 7602176);          // 3,538,944
  ushort* P3b  = (ushort*)(ws + 22282240);         // 1,835,008  (2,64,28,256)
  ushort* A4b  = (ushort*)(ws + 24117248);         // 3,407,872  (2,128,26,256)
  ushort* P5b  = (ushort*)(ws + 33816576);         // 786,432    (2,128,12,128)
  ushort* P6b  = (ushort*)(ws + 35258368);         // 163,840    (2,128,5,64)
  float*  A7   = (float*) (ws + 35422208);         // 1,572,864  (2,256,3,64)
  float*  comat= (float*) (ws + 36995072);         // 393,216
  ushort* Wb2  = (ushort*)(ws + 37388288);         // 73,728
  ushort* Wb4  = (ushort*)(ws + 37462016);         // 147,456
  ushort* Wb5  = (ushort*)(ws + 37609472);         // 294,912
  ushort* Wb6  = (ushort*)(ws + 37904384);         // 294,912
  ushort* Wb7  = (ushort*)(ws + 38199296);         // 589,824
  float*  map6 = (float*) (ws + 38789120);         // 131,072
  float*  map1 = (float*) (ws + 38920192);         // 1,536
  float*  map2 = (float*) (ws + 38921728);         // 3,072
  int*    clsb = (int*)   (ws + 38924800);         // 1,024
  int*    order= (int*)   (ws + 38925824);         // 1,024
  int*    cntv = (int*)   (ws + 38926848);         // 320
  int*    offv = (int*)   (ws + 38927168);         // 320

  setup_kernel<<<2,256,0,stream>>>(g_style, sp1, sp2, c1w1, c1b1, c2w, c2b, label,
                                   map1, map2, clsb, cntv, offv, order);
  repack_all<<<2736,256,0,stream>>>(c1w1, c1w2, c2w, c3w1, c3w2, Wb2, Wb4, Wb5, Wb6, Wb7);
  map6_kernel<<<128,256,0,stream>>>(spaced, label, c3w1, c3b1, map6);

  // h1 (bf16), LDS-staged
  conv_in_kernel<<<dim3(116,8,2),256,0,stream>>>(x, in_w, in_b, h1b);
  // A2+P3 fused: lrelu(conv(h1)+map1) pooled -> P3b (2,64,28,256)
  conv_mfma_pool<64,512,58,64,1><<<dim3(224,1,2),256,0,stream>>>(h1b, Wb2, map1, P3b);
  // A4 = lrelu(conv(P3) + b) : MFMA, bf16 out (2,128,26,256)
  conv_mfma<64,256,28,128,0,1><<<dim3(104,2,2),256,0,stream>>>(P3b, Wb4, c1b2, nullptr, A4b);
  // A5+P5 fused: lrelu(conv(A4)+map2) pooled -> P5b (2,128,12,128)
  conv_mfma_pool<128,256,26,128,1><<<dim3(48,2,2),256,0,stream>>>(A4b, Wb5, map2, P5b);
  // A6+P6 fused: lrelu(conv(P5)+map6) pooled -> P6b (2,128,5,64)
  conv_mfma_pool<128,128,12,128,2><<<dim3(10,2,2),256,0,stream>>>(P5b, Wb6, map6, P6b);
  // A7 = lrelu(conv(P6) + b) : MFMA, f32 out
  conv_mfma<128,64,5,256,0,0><<<dim3(3,4,2),256,0,stream>>>(P6b, Wb7, c3b2, A7, nullptr);
  // pM
  fm_kernel<<<128,256,0,stream>>>(A7, fm_w, fm_b, out);
  // pChar: im2col(bf16) -> grouped-GEMM conv -> tail
  im2col_kernel<<<6912,256,0,stream>>>(A7, pwgh);
  cd_conv_kernel<<<dim3(80,8),256,0,stream>>>(pwgh, cntv, offv, order, cdw, comat);
  cd_tail_kernel<<<256,128,0,stream>>>(comat, clsb, cdb, cstyle, fc1w, fc1b, fc2w, fc2b, out + 128);
}

// Round 15
// 282.018 us; speedup vs baseline: 1.2069x; 1.2069x over previous
//
#include <hip/hip_runtime.h>
#include <hip/hip_bf16.h>

#define LEAKC 0.1f

__device__ __forceinline__ float lrelu(float v){ return v > 0.f ? v : LEAKC*v; }
__device__ __forceinline__ ushort f2b(float f){
  __hip_bfloat16 h = __float2bfloat16(f);
  return *reinterpret_cast<ushort*>(&h);
}
__device__ __forceinline__ float b2f(ushort u){
  __hip_bfloat16 h = *reinterpret_cast<__hip_bfloat16*>(&u);
  return __bfloat162float(h);
}

typedef __attribute__((ext_vector_type(8))) short bf16x8;
typedef __attribute__((ext_vector_type(4))) float f32x4;

__device__ __forceinline__ void pack1(int idx, const float* __restrict__ w,
                                      ushort* __restrict__ wb, int CM, int CTOT){
  int c = idx % CM; int r = idx / CM; int t = r % 9; int n = r / 9;
  wb[idx] = f2b(w[((size_t)n*CTOT + c)*9 + t]);
}

// ---------------- prep: block0 = styles+map1+map2; block1 = sort; 2..129 = map6; 130..2865 = repack ----------------
__global__ __launch_bounds__(256) void prep_kernel(
    const float* __restrict__ g, const float* __restrict__ sp1, const float* __restrict__ sp2,
    const float* __restrict__ c1w1, const float* __restrict__ c1b1,
    const float* __restrict__ c1w2,
    const float* __restrict__ c2w,  const float* __restrict__ c2b,
    const float* __restrict__ c3w1, const float* __restrict__ c3b1,
    const float* __restrict__ c3w2,
    const float* __restrict__ label, const float* __restrict__ spaced,
    float* __restrict__ map1, float* __restrict__ map2, float* __restrict__ map6,
    int* __restrict__ clsb, int* __restrict__ cnt, int* __restrict__ off, int* __restrict__ order,
    ushort* __restrict__ Wb2, ushort* __restrict__ Wb4, ushort* __restrict__ Wb5,
    ushort* __restrict__ Wb6, ushort* __restrict__ Wb7){
  int t = threadIdx.x;
  int bid = blockIdx.x;
  if (bid == 0){
    __shared__ float s1s[64], s2s[128];
    if (t < 64){
      int b = t >> 5, j = t & 31;
      float a = 0.f;
      for (int k=0;k<256;k++) a += g[b*256+k]*sp1[j*256+k];
      s1s[t] = a;
    } else if (t < 192){
      int u = t - 64;
      int b = u >> 6, j = u & 63;
      float a = 0.f;
      for (int k=0;k<256;k++) a += g[b*256+k]*sp2[j*256+k];
      s2s[u] = a;
    }
    __syncthreads();
    if (t < 128){           // map1
      int b = t >> 6, o = t & 63;
      float S0=0.f,S1=0.f,S2=0.f;
      for (int c=0;c<32;c++){
        float s = s1s[b*32+c];
        const float* wq = c1w1 + ((size_t)o*96 + 64 + c)*9;
        S0 += s*(wq[0]+wq[3]+wq[6]);
        S1 += s*(wq[1]+wq[4]+wq[7]);
        S2 += s*(wq[2]+wq[5]+wq[8]);
      }
      float bb = c1b1[o];
      map1[t*3+0]=S1+S2+bb; map1[t*3+1]=S0+S1+S2+bb; map1[t*3+2]=S0+S1+bb;
    }
    {                        // map2
      int b = t >> 7, o = t & 127;
      float S0=0.f,S1=0.f,S2=0.f;
      for (int c=0;c<64;c++){
        float s = s2s[b*64+c];
        const float* wq = c2w + ((size_t)o*192 + 128 + c)*9;
        S0 += s*(wq[0]+wq[3]+wq[6]);
        S1 += s*(wq[1]+wq[4]+wq[7]);
        S2 += s*(wq[2]+wq[5]+wq[8]);
      }
      float bb = c2b[o];
      map2[t*3+0]=S1+S2+bb; map2[t*3+1]=S0+S1+S2+bb; map2[t*3+2]=S0+S1+bb;
    }
  } else if (bid == 1){
    __shared__ int h[80], hoff[80];
    if (t < 80) h[t] = 0;
    __syncthreads();
    int b = t >> 7, tt = t & 127;
    const float* p = label + (tt*2 + b)*80;
    float best = p[0]; int bi = 0;
    for (int c=1;c<80;c++){ float v = p[c]; if (v > best){ best = v; bi = c; } }
    clsb[t] = bi;
    atomicAdd(&h[bi], 1);
    __syncthreads();
    if (t == 0){
      int s = 0;
      for (int e=0;e<80;e++){ hoff[e] = s; s += h[e]; }
    }
    __syncthreads();
    if (t < 80){ cnt[t] = h[t]; off[t] = hoff[t]; }
    __syncthreads();
    int rank = atomicAdd(&hoff[bi], 1);
    order[rank] = t;
  } else if (bid < 130){
    int n = (bid - 2)*256 + t;            // 32768 total
    int w = n & 127, o = (n >> 7) & 127, b = n >> 14;
    float a = c3b1[o];
    #pragma unroll
    for (int tt=0;tt<3;tt++){
      int j = w + tt - 1;
      if (j < 0 || j >= 128) continue;
      const float* sp = spaced + (j*2 + b)*32;
      const float* lb = label + (j*2 + b)*80;
      for (int c=0;c<32;c++){
        const float* wq = c3w1 + ((size_t)o*240 + 128 + c)*9 + tt;
        a += sp[c]*(wq[0]+wq[3]+wq[6]);
      }
      for (int c=0;c<80;c++){
        const float* wq = c3w1 + ((size_t)o*240 + 160 + c)*9 + tt;
        a += lb[c]*(wq[0]+wq[3]+wq[6]);
      }
    }
    map6[n] = a;
  } else {
    int i = (bid - 130)*256 + t;
    if      (i < 36864)  pack1(i,        c1w1, Wb2, 64, 96);
    else if (i < 110592) pack1(i-36864,  c1w2, Wb4, 64, 64);
    else if (i < 258048) pack1(i-110592, c2w,  Wb5, 128, 192);
    else if (i < 405504) pack1(i-258048, c3w1, Wb6, 128, 240);
    else if (i < 700416) pack1(i-405504, c3w2, Wb7, 128, 128);
  }
}

// ---------------- input conv 7x7 -> bf16 out ----------------
__global__ void conv_in_kernel(const float* __restrict__ x,
                               const float* __restrict__ wgt,
                               const float* __restrict__ bias,
                               ushort* __restrict__ out){
  int hw = blockIdx.x*256 + threadIdx.x;
  int y = hw >> 9, w = hw & 511;
  int b = blockIdx.z;
  int o0 = blockIdx.y * 8;
  float acc[8];
  #pragma unroll
  for (int i=0;i<8;i++) acc[i] = bias[o0+i];
  for (int kh=0;kh<7;kh++){
    const float* ip = x + (b*64 + y + kh)*512;
    #pragma unroll
    for (int kw=0;kw<7;kw++){
      int wi = w + kw - 3;
      float v = (wi>=0 && wi<512) ? ip[wi] : 0.f;
      #pragma unroll
      for (int i=0;i<8;i++) acc[i] += v * wgt[(o0+i)*49 + kh*7 + kw];
    }
  }
  #pragma unroll
  for (int i=0;i<8;i++)
    out[((b*64 + o0+i)*58 + y)*512 + w] = f2b(lrelu(acc[i]));
}

// ---------------- MFMA conv: 3x3, pad(0,1), BM=64, BN=64, K=CM*9 ----------------
template<int CM,int WID,int HIN,int COUT,int MODE,int OUTBF>
__global__ __launch_bounds__(256) void conv_mfma(
    const ushort* __restrict__ in,
    const ushort* __restrict__ Wb,
    const float*  __restrict__ mb,
    float* __restrict__ outf,
    ushort* __restrict__ outh){
  constexpr int HOUT = HIN - 2;
  constexpr int KTOT = CM*9;
  constexpr int SLABS = CM/32;
  constexpr int NST = 3*SLABS;
  __shared__ ushort A[2][66][40];
  int tid = threadIdx.x, lane = tid & 63, wave = tid >> 6;
  int mt = blockIdx.x;
  int y  = mt / (WID/64), w0 = (mt % (WID/64))*64;
  int n0 = blockIdx.y*64;
  int b  = blockIdx.z;

  f32x4 acc[4];
  #pragma unroll
  for (int nf=0;nf<4;nf++) acc[nf] = (f32x4){0.f,0.f,0.f,0.f};

  auto stage = [&](int s, int bufi){
    int kh = s / SLABS;
    int c0 = (s % SLABS)*32;
    const ushort* base = in + ((size_t)(b*CM + c0)*HIN + (y+kh))*WID;
    int c2 = (tid & 15)*2, m0v = (tid >> 4)*2*2;
    const ushort* p0 = base + (size_t)c2*HIN*WID + w0 + m0v;
    const ushort* p1 = p0 + (size_t)HIN*WID;
    ushort4 va = *(const ushort4*)p0;
    ushort4 vb = *(const ushort4*)p1;
    uint* dst = (uint*)&A[bufi][1+m0v][c2];
    dst[0]  = (uint)va.x | ((uint)vb.x << 16);
    dst[20] = (uint)va.y | ((uint)vb.y << 16);
    dst[40] = (uint)va.z | ((uint)vb.z << 16);
    dst[60] = (uint)va.w | ((uint)vb.w << 16);
    if (tid < 64){
      int c = tid & 31, side = tid >> 5;
      int w = side ? (w0 + 64) : (w0 - 1);
      ushort v = 0;
      if (w >= 0 && w < WID) v = base[(size_t)c*HIN*WID + w];
      A[bufi][side ? 65 : 0][c] = v;
    }
  };

  stage(0, 0);
  __syncthreads();
  for (int s = 0; s < NST; ++s){
    int cur = s & 1;
    if (s + 1 < NST) stage(s+1, cur ^ 1);
    int kh = s / SLABS;
    int c0 = (s % SLABS)*32;
    #pragma unroll
    for (int kw = 0; kw < 3; ++kw){
      bf16x8 a = *(bf16x8*)&A[cur][wave*16 + (lane & 15) + kw][(lane >> 4)*8];
      #pragma unroll
      for (int nf = 0; nf < 4; ++nf){
        const ushort* wp = Wb + (size_t)(n0 + nf*16 + (lane & 15))*KTOT
                              + (kh*3 + kw)*CM + c0 + (lane >> 4)*8;
        bf16x8 bb = *(const bf16x8*)wp;
        acc[nf] = __builtin_amdgcn_mfma_f32_16x16x32_bf16(a, bb, acc[nf], 0, 0, 0);
      }
    }
    __syncthreads();
  }

  int mrow = wave*16 + ((lane >> 4) << 2);
  int w = w0 + mrow;
  #pragma unroll
  for (int nf = 0; nf < 4; ++nf){
    int n = n0 + nf*16 + (lane & 15);
    float r0 = acc[nf][0], r1 = acc[nf][1], r2 = acc[nf][2], r3 = acc[nf][3];
    if (MODE == 0){
      float bb = mb[n];
      r0 += bb; r1 += bb; r2 += bb; r3 += bb;
    } else if (MODE == 1){
      const float* m3 = mb + (size_t)(b*COUT + n)*3;
      float mL = m3[0], mM = m3[1], mR = m3[2];
      r0 += (w == 0) ? mL : ((w   == WID-1) ? mR : mM);
      r1 += (w+1 == WID-1) ? mR : mM;
      r2 += (w+2 == WID-1) ? mR : mM;
      r3 += (w+3 == WID-1) ? mR : mM;
    } else {
      const float* m6 = mb + ((size_t)(b*COUT + n))*WID + w;
      r0 += m6[0]; r1 += m6[1]; r2 += m6[2]; r3 += m6[3];
    }
    r0 = lrelu(r0); r1 = lrelu(r1); r2 = lrelu(r2); r3 = lrelu(r3);
    size_t off = ((size_t)(b*COUT + n)*HOUT + y)*WID + w;
    if (OUTBF){
      ushort4 o = make_ushort4(f2b(r0), f2b(r1), f2b(r2), f2b(r3));
      *(ushort4*)(outh + off) = o;
    } else {
      *(float4*)(outf + off) = make_float4(r0, r1, r2, r3);
    }
  }
}

// ---------------- 2x2 mean pool (bf16 -> bf16) ----------------
__global__ void pool2_h2h_kernel(const ushort* __restrict__ in, ushort* __restrict__ out,
                                 int H, int W, int total){
  int n = blockIdx.x*256 + threadIdx.x;
  if (n >= total) return;
  int Wo = W >> 1;
  int wo = n % Wo;
  int r = n / Wo;
  int Ho = H >> 1;
  int ho = r % Ho;
  int bc = r / Ho;
  const ushort* p = in + (bc*H + 2*ho)*W + 2*wo;
  out[n] = f2b(0.25f*(b2f(p[0]) + b2f(p[1]) + b2f(p[W]) + b2f(p[W+1])));
}

// ---------------- fm + im2col merged: blocks 0..127 = pM, 128.. = im2col ----------------
__global__ __launch_bounds__(256) void fmim_kernel(const float* __restrict__ A7,
                          const float* __restrict__ fw,
                          const float* __restrict__ fb,
                          float* __restrict__ out,
                          ushort* __restrict__ pwgh){
  if (blockIdx.x < 128){
    __shared__ float red[4];
    int n = blockIdx.x;
    int b = n >> 6, w = n & 63;
    int c = threadIdx.x;
    float a = 0.f;
    #pragma unroll
    for (int r=0;r<3;r++){
      const float* ip = A7 + ((b*256+c)*3+r)*64;
      const float* wp = fw + (c*3+r)*3;
      #pragma unroll
      for (int kw=0;kw<3;kw++){
        int wi = w + kw - 1;
        if (wi>=0 && wi<64) a += ip[wi]*wp[kw];
      }
    }
    #pragma unroll
    for (int off=32; off>0; off>>=1) a += __shfl_down(a, off, 64);
    if ((threadIdx.x & 63) == 0) red[threadIdx.x>>6] = a;
    __syncthreads();
    if (threadIdx.x == 0) out[n] = red[0]+red[1]+red[2]+red[3] + fb[0];
  } else {
    int i = (blockIdx.x - 128)*256 + threadIdx.x;
    if (i >= 256*3*2304) return;
    int d = i % 2304; int rj = i / 2304; int j = rj % 3; int n = rj / 3;
    int b = n >> 7, t = n & 127; int idx = t >> 1;
    int c = d / 9, rem = d - c*9, r = rem / 3, kw = rem - r*3;
    int col = idx - 2 + kw + j;
    pwgh[i] = (col >= 0 && col < 64) ? f2b(A7[((size_t)(b*256 + c)*3 + r)*64 + col]) : (ushort)0;
  }
}

// ---------------- cd conv v6: grouped-GEMM MFMA, uniform work, weights once ----------------
__global__ __launch_bounds__(256) void cd_conv_kernel(
    const ushort* __restrict__ pwgh,  // (256,3,2304) bf16
    const int*   __restrict__ cnt,    // (80)
    const int*   __restrict__ offv,   // (80)
    const int*   __restrict__ order,  // (256)
    const float* __restrict__ Wc,     // (80,128,2304) f32
    float* __restrict__ comat)        // (256,128,3) raw conv outputs
{
  __shared__ int rowOff[48];
  __shared__ f32x4 red[4][3][64];
  int e = blockIdx.x, og = blockIdx.y;
  int m = cnt[e];
  if (m == 0) return;
  int base = offv[e];
  int tid = threadIdx.x, lane = tid & 63, wave = tid >> 6;

  const float* wb_base = Wc + ((size_t)(e*128) + og*16 + (lane & 15))*2304;
  int kbase = wave*576 + ((lane >> 4)*8);

  for (int s0 = 0; s0 < m; s0 += 16){
    int rowsChunk = 3*(m - s0); if (rowsChunk > 48) rowsChunk = 48;
    if (tid < 48){
      int lr = s0 + tid/3;
      rowOff[tid] = (lr < m) ? (order[base+lr]*3 + (tid - (tid/3)*3))*2304 : -1;
    }
    __syncthreads();

    int offA[3];
    #pragma unroll
    for (int mt=0; mt<3; mt++) offA[mt] = rowOff[mt*16 + (lane & 15)];

    f32x4 acc[3];
    #pragma unroll
    for (int mt=0; mt<3; mt++) acc[mt] = (f32x4){0.f,0.f,0.f,0.f};

    for (int kk = 0; kk < 18; ++kk){
      int k0 = kbase + kk*32;
      const float* wb = wb_base + k0;
      float4 wv0 = *(const float4*)wb;
      float4 wv1 = *(const float4*)(wb + 4);
      bf16x8 bfr = { (short)f2b(wv0.x), (short)f2b(wv0.y), (short)f2b(wv0.z), (short)f2b(wv0.w),
                     (short)f2b(wv1.x), (short)f2b(wv1.y), (short)f2b(wv1.z), (short)f2b(wv1.w) };
      #pragma unroll
      for (int mt=0; mt<3; mt++){
        if (mt*16 < rowsChunk){
          bf16x8 af = {0,0,0,0,0,0,0,0};
          if (offA[mt] >= 0) af = *(const bf16x8*)&pwgh[offA[mt] + k0];
          acc[mt] = __builtin_amdgcn_mfma_f32_16x16x32_bf16(af, bfr, acc[mt], 0, 0, 0);
        }
      }
    }

    #pragma unroll
    for (int mt=0; mt<3; mt++) red[wave][mt][lane] = acc[mt];
    __syncthreads();

    if (wave < 3){
      int mt = wave;
      if (mt*16 < rowsChunk){
        f32x4 s4 = red[0][mt][lane];
        #pragma unroll
        for (int w2=1; w2<4; w2++){
          f32x4 t4 = red[w2][mt][lane];
          s4[0]+=t4[0]; s4[1]+=t4[1]; s4[2]+=t4[2]; s4[3]+=t4[3];
        }
        int col = og*16 + (lane & 15);
        #pragma unroll
        for (int r=0; r<4; r++){
          int row = mt*16 + ((lane >> 4) << 2) + r;
          if (row < rowsChunk){
            int lrank = s0 + row/3, j = row - (row/3)*3;
            int n = order[base + lrank];
            comat[((size_t)n*128 + col)*3 + j] = s4[r];
          }
        }
      }
    }
    __syncthreads();
  }
}

// ---------------- cd tail: comat -> pooled feat -> fc1 -> fc2 ----------------
__global__ __launch_bounds__(128) void cd_tail_kernel(
    const float* __restrict__ comat,
    const int*   __restrict__ clsb,
    const float* __restrict__ bcv,
    const float* __restrict__ cstyle,
    const float* __restrict__ W1,
    const float* __restrict__ b1,
    const float* __restrict__ W2,
    const float* __restrict__ b2,
    float* __restrict__ pChar)
{
  __shared__ float feat[160];
  __shared__ float red2[2];
  int n = blockIdx.x, tid = threadIdx.x;
  int b = n >> 7;
  int e = clsb[n];
  int o = tid;
  const float* cm = comat + ((size_t)n*128 + o)*3;
  float bb = bcv[e*128 + o];
  feat[o] = (lrelu(cm[0]+bb) + lrelu(cm[1]+bb) + lrelu(cm[2]+bb)) * (1.f/3.f);
  if (tid < 32) feat[128+tid] = cstyle[(b*80 + e)*32 + tid];
  __syncthreads();

  float s = b1[e*128 + o];
  for (int d=0;d<160;d++) s += feat[d]*W1[(e*160 + d)*128 + o];
  float h = s > 0.f ? s : 0.f;
  float contrib = h * W2[e*128 + o];
  #pragma unroll
  for (int off=32; off>0; off>>=1) contrib += __shfl_down(contrib, off, 64);
  if ((tid & 63) == 0) red2[tid>>6] = contrib;
  __syncthreads();
  if (tid == 0) pChar[n] = red2[0] + red2[1] + b2[e];
}

extern "C" void kernel_launch(void* const* d_in, const int* in_sizes, int n_in,
                              void* d_out, int out_size, void* d_ws, size_t ws_size,
                              hipStream_t stream){
  (void)in_sizes; (void)n_in; (void)out_size; (void)ws_size;
  const float* x      = (const float*)d_in[0];
  const float* label  = (const float*)d_in[1];
  const float* g_style= (const float*)d_in[2];
  const float* spaced = (const float*)d_in[3];
  const float* cstyle = (const float*)d_in[4];
  const float* sp1    = (const float*)d_in[5];
  const float* sp2    = (const float*)d_in[6];
  const float* in_w   = (const float*)d_in[7];
  const float* in_b   = (const float*)d_in[8];
  const float* c1w1   = (const float*)d_in[9];
  const float* c1b1   = (const float*)d_in[10];
  const float* c1w2   = (const float*)d_in[11];
  const float* c1b2   = (const float*)d_in[12];
  const float* c2w    = (const float*)d_in[13];
  const float* c2b    = (const float*)d_in[14];
  const float* c3w1   = (const float*)d_in[15];
  const float* c3b1   = (const float*)d_in[16];
  const float* c3w2   = (const float*)d_in[17];
  const float* c3b2   = (const float*)d_in[18];
  const float* fm_w   = (const float*)d_in[19];
  const float* fm_b   = (const float*)d_in[20];
  const float* cdw    = (const float*)d_in[21];
  const float* cdb    = (const float*)d_in[22];
  const float* fc1w   = (const float*)d_in[23];
  const float* fc1b   = (const float*)d_in[24];
  const float* fc2w   = (const float*)d_in[25];
  const float* fc2b   = (const float*)d_in[26];
  float* out = (float*)d_out;
  char* ws = (char*)d_ws;

  ushort* h1b  = (ushort*)(ws + 0);                // 7,602,176
  ushort* A2h  = (ushort*)(ws + 7602176);          // 7,340,032
  ushort* pwgh = (ushort*)(ws + 7602176);          // 3,538,944 (A2h dead by then)
  ushort* P3b  = (ushort*)(ws + 22282240);         // 1,835,008
  ushort* A4b  = (ushort*)(ws + 24117248);         // 3,407,872
  ushort* A5h  = (ushort*)(ws + 27525120);         // 3,145,728
  ushort* P5b  = (ushort*)(ws + 33816576);         // 786,432
  ushort* A6b  = (ushort*)(ws + 34603008);         // 655,360
  ushort* P6b  = (ushort*)(ws + 35258368);         // 163,840
  float*  A7   = (float*) (ws + 35422208);         // 1,572,864
  float*  comat= (float*) (ws + 36995072);         // 393,216
  ushort* Wb2  = (ushort*)(ws + 37388288);         // 73,728
  ushort* Wb4  = (ushort*)(ws + 37462016);         // 147,456
  ushort* Wb5  = (ushort*)(ws + 37609472);         // 294,912
  ushort* Wb6  = (ushort*)(ws + 37904384);         // 294,912
  ushort* Wb7  = (ushort*)(ws + 38199296);         // 589,824
  float*  map6 = (float*) (ws + 38789120);         // 131,072
  float*  map1 = (float*) (ws + 38920192);         // 1,536
  float*  map2 = (float*) (ws + 38921728);         // 3,072
  int*    clsb = (int*)   (ws + 38924800);         // 1,024
  int*    order= (int*)   (ws + 38925824);         // 1,024
  int*    cntv = (int*)   (ws + 38926848);         // 320
  int*    offv = (int*)   (ws + 38927168);         // 320

  // prep: setup + sort + map6 + all repacks in one dispatch
  prep_kernel<<<2866,256,0,stream>>>(g_style, sp1, sp2, c1w1, c1b1, c1w2, c2w, c2b,
                                     c3w1, c3b1, c3w2, label, spaced,
                                     map1, map2, map6, clsb, cntv, offv, order,
                                     Wb2, Wb4, Wb5, Wb6, Wb7);

  // h1 (bf16)
  conv_in_kernel<<<dim3(116,8,2),256,0,stream>>>(x, in_w, in_b, h1b);
  // A2 = lrelu(conv(h1) + map1) : MFMA, bf16 out
  conv_mfma<64,512,58,64,1,1><<<dim3(448,1,2),256,0,stream>>>(h1b, Wb2, map1, nullptr, A2h);
  // P3 (bf16 -> bf16)
  pool2_h2h_kernel<<<3584,256,0,stream>>>(A2h, P3b, 56, 512, 917504);
  // A4 = lrelu(conv(P3) + b) : MFMA, bf16 out
  conv_mfma<64,256,28,128,0,1><<<dim3(104,2,2),256,0,stream>>>(P3b, Wb4, c1b2, nullptr, A4b);
  // A5 = lrelu(conv(A4) + map2) : MFMA, bf16 out
  conv_mfma<128,256,26,128,1,1><<<dim3(96,2,2),256,0,stream>>>(A4b, Wb5, map2, nullptr, A5h);
  // P5 (bf16 -> bf16)
  pool2_h2h_kernel<<<1536,256,0,stream>>>(A5h, P5b, 24, 256, 393216);
  // A6 = lrelu(conv(P5) + map6) : MFMA MODE2, bf16 out
  conv_mfma<128,128,12,128,2,1><<<dim3(20,2,2),256,0,stream>>>(P5b, Wb6, map6, nullptr, A6b);
  // P6 (bf16 -> bf16)
  pool2_h2h_kernel<<<320,256,0,stream>>>(A6b, P6b, 10, 128, 81920);
  // A7 = lrelu(conv(P6) + b) : MFMA, f32 out
  conv_mfma<128,64,5,256,0,0><<<dim3(3,4,2),256,0,stream>>>(P6b, Wb7, c3b2, A7, nullptr);
  // pM + im2col (independent, merged)
  fmim_kernel<<<7040,256,0,stream>>>(A7, fm_w, fm_b, out, pwgh);
  // pChar: grouped-GEMM conv -> tail
  cd_conv_kernel<<<dim3(80,8),256,0,stream>>>(pwgh, cntv, offv, order, cdw, comat);
  cd_tail_kernel<<<256,128,0,stream>>>(comat, clsb, cdb, cstyle, fc1w, fc1b, fc2w, fc2b, out + 128);
}

// Round 16
// 248.572 us; speedup vs baseline: 1.3693x; 1.1346x over previous
//
#include <hip/hip_runtime.h>
#include <hip/hip_bf16.h>

#define LEAKC 0.1f

__device__ __forceinline__ float lrelu(float v){ return v > 0.f ? v : LEAKC*v; }
__device__ __forceinline__ ushort f2b(float f){
  __hip_bfloat16 h = __float2bfloat16(f);
  return *reinterpret_cast<ushort*>(&h);
}
__device__ __forceinline__ float b2f(ushort u){
  __hip_bfloat16 h = *reinterpret_cast<__hip_bfloat16*>(&u);
  return __bfloat162float(h);
}

typedef __attribute__((ext_vector_type(8))) short bf16x8;
typedef __attribute__((ext_vector_type(4))) float f32x4;
typedef __attribute__((ext_vector_type(8))) unsigned short ushort8;

__device__ __forceinline__ void pack1(int idx, const float* __restrict__ w,
                                      ushort* __restrict__ wb, int CM, int CTOT){
  int c = idx % CM; int r = idx / CM; int t = r % 9; int n = r / 9;
  wb[idx] = f2b(w[((size_t)n*CTOT + c)*9 + t]);
}

// ---------------- prep: 0=styles+maps; 1=sort; 2..129=map6; 130..2865=repack; 2866..4721=conv_in ----------------
__global__ __launch_bounds__(256) void prep_kernel(
    const float* __restrict__ g, const float* __restrict__ sp1, const float* __restrict__ sp2,
    const float* __restrict__ c1w1, const float* __restrict__ c1b1,
    const float* __restrict__ c1w2,
    const float* __restrict__ c2w,  const float* __restrict__ c2b,
    const float* __restrict__ c3w1, const float* __restrict__ c3b1,
    const float* __restrict__ c3w2,
    const float* __restrict__ label, const float* __restrict__ spaced,
    const float* __restrict__ x, const float* __restrict__ in_w, const float* __restrict__ in_b,
    float* __restrict__ map1, float* __restrict__ map2, float* __restrict__ map6,
    int* __restrict__ clsb, int* __restrict__ cnt, int* __restrict__ off, int* __restrict__ order,
    ushort* __restrict__ Wb2, ushort* __restrict__ Wb4, ushort* __restrict__ Wb5,
    ushort* __restrict__ Wb6, ushort* __restrict__ Wb7,
    ushort* __restrict__ h1b){
  int t = threadIdx.x;
  int bid = blockIdx.x;
  if (bid == 0){
    __shared__ float s1s[64], s2s[128];
    if (t < 64){
      int b = t >> 5, j = t & 31;
      float a = 0.f;
      for (int k=0;k<256;k++) a += g[b*256+k]*sp1[j*256+k];
      s1s[t] = a;
    } else if (t < 192){
      int u = t - 64;
      int b = u >> 6, j = u & 63;
      float a = 0.f;
      for (int k=0;k<256;k++) a += g[b*256+k]*sp2[j*256+k];
      s2s[u] = a;
    }
    __syncthreads();
    if (t < 128){           // map1
      int b = t >> 6, o = t & 63;
      float S0=0.f,S1=0.f,S2=0.f;
      for (int c=0;c<32;c++){
        float s = s1s[b*32+c];
        const float* wq = c1w1 + ((size_t)o*96 + 64 + c)*9;
        S0 += s*(wq[0]+wq[3]+wq[6]);
        S1 += s*(wq[1]+wq[4]+wq[7]);
        S2 += s*(wq[2]+wq[5]+wq[8]);
      }
      float bb = c1b1[o];
      map1[t*3+0]=S1+S2+bb; map1[t*3+1]=S0+S1+S2+bb; map1[t*3+2]=S0+S1+bb;
    }
    {                        // map2
      int b = t >> 7, o = t & 127;
      float S0=0.f,S1=0.f,S2=0.f;
      for (int c=0;c<64;c++){
        float s = s2s[b*64+c];
        const float* wq = c2w + ((size_t)o*192 + 128 + c)*9;
        S0 += s*(wq[0]+wq[3]+wq[6]);
        S1 += s*(wq[1]+wq[4]+wq[7]);
        S2 += s*(wq[2]+wq[5]+wq[8]);
      }
      float bb = c2b[o];
      map2[t*3+0]=S1+S2+bb; map2[t*3+1]=S0+S1+S2+bb; map2[t*3+2]=S0+S1+bb;
    }
  } else if (bid == 1){
    __shared__ int h[80], hoff[80];
    if (t < 80) h[t] = 0;
    __syncthreads();
    int b = t >> 7, tt = t & 127;
    const float* p = label + (tt*2 + b)*80;
    float best = p[0]; int bi = 0;
    for (int c=1;c<80;c++){ float v = p[c]; if (v > best){ best = v; bi = c; } }
    clsb[t] = bi;
    atomicAdd(&h[bi], 1);
    __syncthreads();
    if (t == 0){
      int s = 0;
      for (int e=0;e<80;e++){ hoff[e] = s; s += h[e]; }
    }
    __syncthreads();
    if (t < 80){ cnt[t] = h[t]; off[t] = hoff[t]; }
    __syncthreads();
    int rank = atomicAdd(&hoff[bi], 1);
    order[rank] = t;
  } else if (bid < 130){
    int n = (bid - 2)*256 + t;            // 32768 total
    int w = n & 127, o = (n >> 7) & 127, b = n >> 14;
    float a = c3b1[o];
    #pragma unroll
    for (int tt=0;tt<3;tt++){
      int j = w + tt - 1;
      if (j < 0 || j >= 128) continue;
      const float* sp = spaced + (j*2 + b)*32;
      const float* lb = label + (j*2 + b)*80;
      for (int c=0;c<32;c++){
        const float* wq = c3w1 + ((size_t)o*240 + 128 + c)*9 + tt;
        a += sp[c]*(wq[0]+wq[3]+wq[6]);
      }
      for (int c=0;c<80;c++){
        const float* wq = c3w1 + ((size_t)o*240 + 160 + c)*9 + tt;
        a += lb[c]*(wq[0]+wq[3]+wq[6]);
      }
    }
    map6[n] = a;
  } else if (bid < 2866){
    int i = (bid - 130)*256 + t;
    if      (i < 36864)  pack1(i,        c1w1, Wb2, 64, 96);
    else if (i < 110592) pack1(i-36864,  c1w2, Wb4, 64, 64);
    else if (i < 258048) pack1(i-110592, c2w,  Wb5, 128, 192);
    else if (i < 405504) pack1(i-258048, c3w1, Wb6, 128, 240);
    else if (i < 700416) pack1(i-405504, c3w2, Wb7, 128, 128);
  } else {
    // conv_in: 1856 blocks = (xb 116, og 8, b 2)
    int bid2 = bid - 2866;
    int xb = bid2 % 116;
    int og = (bid2 / 116) & 7;
    int b  = bid2 / (116*8);
    int hw = xb*256 + t;                 // < 58*512
    int y = hw >> 9, w = hw & 511;
    int o0 = og * 8;
    float acc[8];
    #pragma unroll
    for (int i=0;i<8;i++) acc[i] = in_b[o0+i];
    for (int kh=0;kh<7;kh++){
      const float* ip = x + ((size_t)b*64 + y + kh)*512;
      #pragma unroll
      for (int kw=0;kw<7;kw++){
        int wi = w + kw - 3;
        float v = (wi>=0 && wi<512) ? ip[wi] : 0.f;
        #pragma unroll
        for (int i=0;i<8;i++) acc[i] += v * in_w[(o0+i)*49 + kh*7 + kw];
      }
    }
    #pragma unroll
    for (int i=0;i<8;i++)
      h1b[((size_t)(b*64 + o0+i)*58 + y)*512 + w] = f2b(lrelu(acc[i]));
  }
}

// ---------------- MFMA conv: 3x3, pad(0,1), BM=64, BN=64, K=CM*9 ----------------
// POOLIN: input is full-res (2,CM,2*HIN,2*WID); stage computes 2x2 mean inline.
template<int CM,int WID,int HIN,int COUT,int MODE,int OUTBF,int POOLIN>
__global__ __launch_bounds__(256) void conv_mfma(
    const ushort* __restrict__ in,
    const ushort* __restrict__ Wb,
    const float*  __restrict__ mb,
    float* __restrict__ outf,
    ushort* __restrict__ outh){
  constexpr int HOUT = HIN - 2;
  constexpr int KTOT = CM*9;
  constexpr int SLABS = CM/32;
  constexpr int NST = 3*SLABS;
  constexpr int HINF = 2*HIN;
  constexpr int WIDF = 2*WID;
  __shared__ ushort A[2][66][40];
  int tid = threadIdx.x, lane = tid & 63, wave = tid >> 6;
  int mt = blockIdx.x;
  int y  = mt / (WID/64), w0 = (mt % (WID/64))*64;
  int n0 = blockIdx.y*64;
  int b  = blockIdx.z;

  f32x4 acc[4];
  #pragma unroll
  for (int nf=0;nf<4;nf++) acc[nf] = (f32x4){0.f,0.f,0.f,0.f};

  auto stage = [&](int s, int bufi){
    int kh = s / SLABS;
    int c0s = (s % SLABS)*32;
    int c2 = (tid & 15)*2, m0v = (tid >> 4)*4;
    uint* dst = (uint*)&A[bufi][1+m0v][c2];
    if (POOLIN){
      const ushort* q0 = in + ((size_t)(b*CM + c0s + c2)*HINF + 2*(y+kh))*WIDF + 2*(w0 + m0v);
      const ushort* q1 = q0 + (size_t)HINF*WIDF;
      ushort8 a0 = *(const ushort8*)q0;
      ushort8 a1 = *(const ushort8*)(q0 + WIDF);
      ushort8 b0 = *(const ushort8*)q1;
      ushort8 b1 = *(const ushort8*)(q1 + WIDF);
      #pragma unroll
      for (int k=0;k<4;k++){
        float pa = 0.25f*(b2f(a0[2*k])+b2f(a0[2*k+1])+b2f(a1[2*k])+b2f(a1[2*k+1]));
        float pb = 0.25f*(b2f(b0[2*k])+b2f(b0[2*k+1])+b2f(b1[2*k])+b2f(b1[2*k+1]));
        dst[k*20] = (uint)f2b(pa) | ((uint)f2b(pb) << 16);
      }
      if (tid < 64){
        int c = tid & 31, side = tid >> 5;
        int wp = side ? (w0 + 64) : (w0 - 1);
        ushort v = 0;
        if (wp >= 0 && wp < WID){
          const ushort* q = in + ((size_t)(b*CM + c0s + c)*HINF + 2*(y+kh))*WIDF + 2*wp;
          v = f2b(0.25f*(b2f(q[0])+b2f(q[1])+b2f(q[WIDF])+b2f(q[WIDF+1])));
        }
        A[bufi][side ? 65 : 0][c] = v;
      }
    } else {
      const ushort* base = in + ((size_t)(b*CM + c0s)*HIN + (y+kh))*WID;
      const ushort* p0 = base + (size_t)c2*HIN*WID + w0 + m0v;
      const ushort* p1 = p0 + (size_t)HIN*WID;
      ushort4 va = *(const ushort4*)p0;
      ushort4 vb = *(const ushort4*)p1;
      dst[0]  = (uint)va.x | ((uint)vb.x << 16);
      dst[20] = (uint)va.y | ((uint)vb.y << 16);
      dst[40] = (uint)va.z | ((uint)vb.z << 16);
      dst[60] = (uint)va.w | ((uint)vb.w << 16);
      if (tid < 64){
        int c = tid & 31, side = tid >> 5;
        int w = side ? (w0 + 64) : (w0 - 1);
        ushort v = 0;
        if (w >= 0 && w < WID) v = base[(size_t)c*HIN*WID + w];
        A[bufi][side ? 65 : 0][c] = v;
      }
    }
  };

  stage(0, 0);
  __syncthreads();
  for (int s = 0; s < NST; ++s){
    int cur = s & 1;
    if (s + 1 < NST) stage(s+1, cur ^ 1);
    int kh = s / SLABS;
    int c0 = (s % SLABS)*32;
    #pragma unroll
    for (int kw = 0; kw < 3; ++kw){
      bf16x8 a = *(bf16x8*)&A[cur][wave*16 + (lane & 15) + kw][(lane >> 4)*8];
      #pragma unroll
      for (int nf = 0; nf < 4; ++nf){
        const ushort* wp = Wb + (size_t)(n0 + nf*16 + (lane & 15))*KTOT
                              + (kh*3 + kw)*CM + c0 + (lane >> 4)*8;
        bf16x8 bb = *(const bf16x8*)wp;
        acc[nf] = __builtin_amdgcn_mfma_f32_16x16x32_bf16(a, bb, acc[nf], 0, 0, 0);
      }
    }
    __syncthreads();
  }

  int mrow = wave*16 + ((lane >> 4) << 2);
  int w = w0 + mrow;
  #pragma unroll
  for (int nf = 0; nf < 4; ++nf){
    int n = n0 + nf*16 + (lane & 15);
    float r0 = acc[nf][0], r1 = acc[nf][1], r2 = acc[nf][2], r3 = acc[nf][3];
    if (MODE == 0){
      float bb = mb[n];
      r0 += bb; r1 += bb; r2 += bb; r3 += bb;
    } else if (MODE == 1){
      const float* m3 = mb + (size_t)(b*COUT + n)*3;
      float mL = m3[0], mM = m3[1], mR = m3[2];
      r0 += (w == 0) ? mL : ((w   == WID-1) ? mR : mM);
      r1 += (w+1 == WID-1) ? mR : mM;
      r2 += (w+2 == WID-1) ? mR : mM;
      r3 += (w+3 == WID-1) ? mR : mM;
    } else {
      const float* m6 = mb + ((size_t)(b*COUT + n))*WID + w;
      r0 += m6[0]; r1 += m6[1]; r2 += m6[2]; r3 += m6[3];
    }
    r0 = lrelu(r0); r1 = lrelu(r1); r2 = lrelu(r2); r3 = lrelu(r3);
    size_t off = ((size_t)(b*COUT + n)*HOUT + y)*WID + w;
    if (OUTBF){
      ushort4 o = make_ushort4(f2b(r0), f2b(r1), f2b(r2), f2b(r3));
      *(ushort4*)(outh + off) = o;
    } else {
      *(float4*)(outf + off) = make_float4(r0, r1, r2, r3);
    }
  }
}

// ---------------- fm + im2col merged: blocks 0..127 = pM, 128.. = im2col ----------------
__global__ __launch_bounds__(256) void fmim_kernel(const float* __restrict__ A7,
                          const float* __restrict__ fw,
                          const float* __restrict__ fb,
                          float* __restrict__ out,
                          ushort* __restrict__ pwgh){
  if (blockIdx.x < 128){
    __shared__ float red[4];
    int n = blockIdx.x;
    int b = n >> 6, w = n & 63;
    int c = threadIdx.x;
    float a = 0.f;
    #pragma unroll
    for (int r=0;r<3;r++){
      const float* ip = A7 + ((b*256+c)*3+r)*64;
      const float* wp = fw + (c*3+r)*3;
      #pragma unroll
      for (int kw=0;kw<3;kw++){
        int wi = w + kw - 1;
        if (wi>=0 && wi<64) a += ip[wi]*wp[kw];
      }
    }
    #pragma unroll
    for (int off=32; off>0; off>>=1) a += __shfl_down(a, off, 64);
    if ((threadIdx.x & 63) == 0) red[threadIdx.x>>6] = a;
    __syncthreads();
    if (threadIdx.x == 0) out[n] = red[0]+red[1]+red[2]+red[3] + fb[0];
  } else {
    int i = (blockIdx.x - 128)*256 + threadIdx.x;
    if (i >= 256*3*2304) return;
    int d = i % 2304; int rj = i / 2304; int j = rj % 3; int n = rj / 3;
    int b = n >> 7, t = n & 127; int idx = t >> 1;
    int c = d / 9, rem = d - c*9, r = rem / 3, kw = rem - r*3;
    int col = idx - 2 + kw + j;
    pwgh[i] = (col >= 0 && col < 64) ? f2b(A7[((size_t)(b*256 + c)*3 + r)*64 + col]) : (ushort)0;
  }
}

// ---------------- cd conv v6: grouped-GEMM MFMA, uniform work, weights once ----------------
__global__ __launch_bounds__(256) void cd_conv_kernel(
    const ushort* __restrict__ pwgh,  // (256,3,2304) bf16
    const int*   __restrict__ cnt,    // (80)
    const int*   __restrict__ offv,   // (80)
    const int*   __restrict__ order,  // (256)
    const float* __restrict__ Wc,     // (80,128,2304) f32
    float* __restrict__ comat)        // (256,128,3) raw conv outputs
{
  __shared__ int rowOff[48];
  __shared__ f32x4 red[4][3][64];
  int e = blockIdx.x, og = blockIdx.y;
  int m = cnt[e];
  if (m == 0) return;
  int base = offv[e];
  int tid = threadIdx.x, lane = tid & 63, wave = tid >> 6;

  const float* wb_base = Wc + ((size_t)(e*128) + og*16 + (lane & 15))*2304;
  int kbase = wave*576 + ((lane >> 4)*8);

  for (int s0 = 0; s0 < m; s0 += 16){
    int rowsChunk = 3*(m - s0); if (rowsChunk > 48) rowsChunk = 48;
    if (tid < 48){
      int lr = s0 + tid/3;
      rowOff[tid] = (lr < m) ? (order[base+lr]*3 + (tid - (tid/3)*3))*2304 : -1;
    }
    __syncthreads();

    int offA[3];
    #pragma unroll
    for (int mt=0; mt<3; mt++) offA[mt] = rowOff[mt*16 + (lane & 15)];

    f32x4 acc[3];
    #pragma unroll
    for (int mt=0; mt<3; mt++) acc[mt] = (f32x4){0.f,0.f,0.f,0.f};

    for (int kk = 0; kk < 18; ++kk){
      int k0 = kbase + kk*32;
      const float* wb = wb_base + k0;
      float4 wv0 = *(const float4*)wb;
      float4 wv1 = *(const float4*)(wb + 4);
      bf16x8 bfr = { (short)f2b(wv0.x), (short)f2b(wv0.y), (short)f2b(wv0.z), (short)f2b(wv0.w),
                     (short)f2b(wv1.x), (short)f2b(wv1.y), (short)f2b(wv1.z), (short)f2b(wv1.w) };
      #pragma unroll
      for (int mt=0; mt<3; mt++){
        if (mt*16 < rowsChunk){
          bf16x8 af = {0,0,0,0,0,0,0,0};
          if (offA[mt] >= 0) af = *(const bf16x8*)&pwgh[offA[mt] + k0];
          acc[mt] = __builtin_amdgcn_mfma_f32_16x16x32_bf16(af, bfr, acc[mt], 0, 0, 0);
        }
      }
    }

    #pragma unroll
    for (int mt=0; mt<3; mt++) red[wave][mt][lane] = acc[mt];
    __syncthreads();

    if (wave < 3){
      int mt = wave;
      if (mt*16 < rowsChunk){
        f32x4 s4 = red[0][mt][lane];
        #pragma unroll
        for (int w2=1; w2<4; w2++){
          f32x4 t4 = red[w2][mt][lane];
          s4[0]+=t4[0]; s4[1]+=t4[1]; s4[2]+=t4[2]; s4[3]+=t4[3];
        }
        int col = og*16 + (lane & 15);
        #pragma unroll
        for (int r=0; r<4; r++){
          int row = mt*16 + ((lane >> 4) << 2) + r;
          if (row < rowsChunk){
            int lrank = s0 + row/3, j = row - (row/3)*3;
            int n = order[base + lrank];
            comat[((size_t)n*128 + col)*3 + j] = s4[r];
          }
        }
      }
    }
    __syncthreads();
  }
}

// ---------------- cd tail: comat -> pooled feat -> fc1 -> fc2 ----------------
__global__ __launch_bounds__(128) void cd_tail_kernel(
    const float* __restrict__ comat,
    const int*   __restrict__ clsb,
    const float* __restrict__ bcv,
    const float* __restrict__ cstyle,
    const float* __restrict__ W1,
    const float* __restrict__ b1,
    const float* __restrict__ W2,
    const float* __restrict__ b2,
    float* __restrict__ pChar)
{
  __shared__ float feat[160];
  __shared__ float red2[2];
  int n = blockIdx.x, tid = threadIdx.x;
  int b = n >> 7;
  int e = clsb[n];
  int o = tid;
  const float* cm = comat + ((size_t)n*128 + o)*3;
  float bb = bcv[e*128 + o];
  feat[o] = (lrelu(cm[0]+bb) + lrelu(cm[1]+bb) + lrelu(cm[2]+bb)) * (1.f/3.f);
  if (tid < 32) feat[128+tid] = cstyle[(b*80 + e)*32 + tid];
  __syncthreads();

  float s = b1[e*128 + o];
  for (int d=0;d<160;d++) s += feat[d]*W1[(e*160 + d)*128 + o];
  float h = s > 0.f ? s : 0.f;
  float contrib = h * W2[e*128 + o];
  #pragma unroll
  for (int off=32; off>0; off>>=1) contrib += __shfl_down(contrib, off, 64);
  if ((tid & 63) == 0) red2[tid>>6] = contrib;
  __syncthreads();
  if (tid == 0) pChar[n] = red2[0] + red2[1] + b2[e];
}

extern "C" void kernel_launch(void* const* d_in, const int* in_sizes, int n_in,
                              void* d_out, int out_size, void* d_ws, size_t ws_size,
                              hipStream_t stream){
  (void)in_sizes; (void)n_in; (void)out_size; (void)ws_size;
  const float* x      = (const float*)d_in[0];
  const float* label  = (const float*)d_in[1];
  const float* g_style= (const float*)d_in[2];
  const float* spaced = (const float*)d_in[3];
  const float* cstyle = (const float*)d_in[4];
  const float* sp1    = (const float*)d_in[5];
  const float* sp2    = (const float*)d_in[6];
  const float* in_w   = (const float*)d_in[7];
  const float* in_b   = (const float*)d_in[8];
  const float* c1w1   = (const float*)d_in[9];
  const float* c1b1   = (const float*)d_in[10];
  const float* c1w2   = (const float*)d_in[11];
  const float* c1b2   = (const float*)d_in[12];
  const float* c2w    = (const float*)d_in[13];
  const float* c2b    = (const float*)d_in[14];
  const float* c3w1   = (const float*)d_in[15];
  const float* c3b1   = (const float*)d_in[16];
  const float* c3w2   = (const float*)d_in[17];
  const float* c3b2   = (const float*)d_in[18];
  const float* fm_w   = (const float*)d_in[19];
  const float* fm_b   = (const float*)d_in[20];
  const float* cdw    = (const float*)d_in[21];
  const float* cdb    = (const float*)d_in[22];
  const float* fc1w   = (const float*)d_in[23];
  const float* fc1b   = (const float*)d_in[24];
  const float* fc2w   = (const float*)d_in[25];
  const float* fc2b   = (const float*)d_in[26];
  float* out = (float*)d_out;
  char* ws = (char*)d_ws;

  ushort* h1b  = (ushort*)(ws + 0);                // 7,602,176  (2,64,58,512)
  ushort* A2h  = (ushort*)(ws + 7602176);          // 7,340,032  (2,64,56,512)
  ushort* pwgh = (ushort*)(ws + 14942208);         // 3,538,944
  ushort* A4b  = (ushort*)(ws + 18481152);         // 3,407,872  (2,128,26,256)
  ushort* A5h  = (ushort*)(ws + 21889024);         // 3,145,728  (2,128,24,256)
  ushort* A6b  = (ushort*)(ws + 25034752);         // 655,360    (2,128,10,128)
  float*  A7   = (float*) (ws + 25690112);         // 1,572,864  (2,256,3,64)
  float*  comat= (float*) (ws + 27262976);         // 393,216
  ushort* Wb2  = (ushort*)(ws + 27656192);         // 73,728
  ushort* Wb4  = (ushort*)(ws + 27729920);         // 147,456
  ushort* Wb5  = (ushort*)(ws + 27877376);         // 294,912
  ushort* Wb6  = (ushort*)(ws + 28172288);         // 294,912
  ushort* Wb7  = (ushort*)(ws + 28467200);         // 589,824
  float*  map6 = (float*) (ws + 29057024);         // 131,072
  float*  map1 = (float*) (ws + 29188096);         // 1,536
  float*  map2 = (float*) (ws + 29189632);         // 3,072
  int*    clsb = (int*)   (ws + 29192704);         // 1,024
  int*    order= (int*)   (ws + 29193728);         // 1,024
  int*    cntv = (int*)   (ws + 29194752);         // 320
  int*    offv = (int*)   (ws + 29195072);         // 320

  // prep: setup + sort + map6 + repacks + conv_in, one dispatch
  prep_kernel<<<4722,256,0,stream>>>(g_style, sp1, sp2, c1w1, c1b1, c1w2, c2w, c2b,
                                     c3w1, c3b1, c3w2, label, spaced,
                                     x, in_w, in_b,
                                     map1, map2, map6, clsb, cntv, offv, order,
                                     Wb2, Wb4, Wb5, Wb6, Wb7, h1b);

  // A2 = lrelu(conv(h1) + map1) : MFMA, bf16 out (2,64,56,512)
  conv_mfma<64,512,58,64,1,1,0><<<dim3(448,1,2),256,0,stream>>>(h1b, Wb2, map1, nullptr, A2h);
  // A4 = lrelu(conv(pool(A2)) + b) : POOLIN, bf16 out (2,128,26,256)
  conv_mfma<64,256,28,128,0,1,1><<<dim3(104,2,2),256,0,stream>>>(A2h, Wb4, c1b2, nullptr, A4b);
  // A5 = lrelu(conv(A4) + map2) : MFMA, bf16 out (2,128,24,256)
  conv_mfma<128,256,26,128,1,1,0><<<dim3(96,2,2),256,0,stream>>>(A4b, Wb5, map2, nullptr, A5h);
  // A6 = lrelu(conv(pool(A5)) + map6) : POOLIN MODE2, bf16 out (2,128,10,128)
  conv_mfma<128,128,12,128,2,1,1><<<dim3(20,2,2),256,0,stream>>>(A5h, Wb6, map6, nullptr, A6b);
  // A7 = lrelu(conv(pool(A6)) + b) : POOLIN, f32 out (2,256,3,64)
  conv_mfma<128,64,5,256,0,0,1><<<dim3(3,4,2),256,0,stream>>>(A6b, Wb7, c3b2, A7, nullptr);
  // pM + im2col (independent, merged)
  fmim_kernel<<<7040,256,0,stream>>>(A7, fm_w, fm_b, out, pwgh);
  // pChar: grouped-GEMM conv -> tail
  cd_conv_kernel<<<dim3(80,8),256,0,stream>>>(pwgh, cntv, offv, order, cdw, comat);
  cd_tail_kernel<<<256,128,0,stream>>>(comat, clsb, cdb, cstyle, fc1w, fc1b, fc2w, fc2b, out + 128);
}